// Round 1
// baseline (698.091 us; speedup 1.0000x reference)
//
#include <hip/hip_runtime.h>

typedef unsigned short u16;
typedef unsigned int   u32;
typedef unsigned long long u64;
typedef short bf16x8 __attribute__((ext_vector_type(8)));   // 8 bf16 (4 VGPRs)
typedef float f32x4  __attribute__((ext_vector_type(4)));

#define N_ROWS 50000
#define D_DIM  2048
#define H_DIM  512
#define KSEL   5000
#define SORT_N 8192

// ---------------- workspace layout (bytes) ----------------
// needs ~6.2 MB of d_ws
#define W1H_OFF    0u         // 512*2048 bf16 hi  (2 MB)
#define W1L_OFF    2097152u   // 512*2048 bf16 lo  (2 MB)
#define PART_OFF   4194304u   // 4 x 50000 f32 partial scores (800 KB)
#define SCORES_OFF 4994304u   // 50000 f32
#define HIST_OFF   5194304u   // 65536 u32 (256 KB)
#define META_OFF   5456448u   // 16 ints: [0]=threshold bin, [1]=compact counter
#define KEYS_OFF   5456512u   // 8192 u64
#define SIDX_OFF   5522048u   // 5000 u32
#define SVAL_OFF   5542048u   // 5000 f32
#define AKW_OFF    5562048u   // 5000 f32
#define GPART_OFF  5582048u   // 64*2048 f32 (512 KB)

__device__ __forceinline__ u32 f2bf_u(float f){
  u32 u = __float_as_uint(f);
  return (u + 0x7FFFu + ((u >> 16) & 1u)) >> 16;   // RNE, no NaN handling (none present)
}
__device__ __forceinline__ float bf2f(u32 h){ return __uint_as_float(h << 16); }
__device__ __forceinline__ u32 mono_bits(float s){   // order-preserving f32 -> u32
  u32 u = __float_as_uint(s);
  return (u & 0x80000000u) ? ~u : (u | 0x80000000u);
}
__device__ __forceinline__ void gload_lds16(const void* g, void* l){
  __builtin_amdgcn_global_load_lds((__attribute__((address_space(1))) void*)(void*)g,
                                   (__attribute__((address_space(3))) void*)l, 16, 0, 0);
}

// ---------------- W1 -> bf16 hi/lo split ----------------
__global__ void prep_w1(const float* __restrict__ w1, u16* __restrict__ w1h, u16* __restrict__ w1l){
  int i = (blockIdx.x * 256 + threadIdx.x) * 4;   // 1024 blocks * 256 thr * 4 = 1048576 exact
  float4 v = *(const float4*)(w1 + i);
  u32 h0 = f2bf_u(v.x), h1 = f2bf_u(v.y), h2 = f2bf_u(v.z), h3 = f2bf_u(v.w);
  u32 l0 = f2bf_u(v.x - bf2f(h0)), l1 = f2bf_u(v.y - bf2f(h1));
  u32 l2 = f2bf_u(v.z - bf2f(h2)), l3 = f2bf_u(v.w - bf2f(h3));
  *(uint2*)(w1h + i) = make_uint2(h0 | (h1 << 16), h2 | (h3 << 16));
  *(uint2*)(w1l + i) = make_uint2(l0 | (l1 << 16), l2 | (l3 << 16));
}

// ---------------- fused scores GEMM ----------------
// grid (782, 4): 64 rows x 128 h-cols per block, K loop over 2048.
// z = x@W1^T via split-bf16 MFMA (xh*wh + xh*wl + xl*wh); epilogue: tanh(z+b1)*W2 summed
// over the block's 128 cols -> partial[by][row].
__global__ __launch_bounds__(256, 3) void gemm_scores(
    const float* __restrict__ x, const u16* __restrict__ w1h, const u16* __restrict__ w1l,
    const float* __restrict__ b1, const float* __restrict__ w2, float* __restrict__ partial)
{
  __shared__ u16 XH[4096], XL[4096];     // 64 rows x 64 k, XOR-swizzled 16B chunks
  __shared__ u16 WH[8192], WL[8192];     // 128 rows x 64 k, same swizzle (via source)
  __shared__ float EPI[64][2];

  const int t  = threadIdx.x;
  const int l  = t & 63, w = t >> 6;
  const int wm = w >> 1, wn = w & 1;     // wave grid 2x2: 32 rows x 64 cols per wave
  const int r0 = blockIdx.x * 64;
  const int h0 = blockIdx.y * 128;

  f32x4 acc[2][4] = {};

  // x staging indices: pass p -> row = p*16 + (t>>4), 4 f32 at k-col (t&15)*4
  const int xr_sub  = t >> 4;
  const int xchunk  = (t & 15) >> 1;     // 16B chunk within row
  const int xoff    = (t & 15) & 1;      // 8B half within chunk
  // W dma: pass p -> row = p*32 + w*8 + (l>>3); source pre-swizzled so LDS stays linear
  const int wrow_sub = w * 8 + (l >> 3);
  const int wchunk   = (l & 7) ^ (l >> 3);       // = chunk_slot ^ (row&7)
  const int wlds_base = w * 512;                 // ushort idx; + p*2048

  const float* xptr[4]; int xlrow[4];
  #pragma unroll
  for (int p = 0; p < 4; ++p){
    int row = p * 16 + xr_sub;
    int gr = r0 + row; if (gr > N_ROWS - 1) gr = N_ROWS - 1;   // clamp tail rows
    xptr[p] = x + (size_t)gr * D_DIM + (t & 15) * 4;
    xlrow[p] = row;
  }
  const u16* wsrcH[4]; const u16* wsrcL[4];
  #pragma unroll
  for (int p = 0; p < 4; ++p){
    int row = p * 32 + wrow_sub;
    wsrcH[p] = w1h + (size_t)(h0 + row) * D_DIM + wchunk * 8;
    wsrcL[p] = w1l + (size_t)(h0 + row) * D_DIM + wchunk * 8;
  }

  for (int k0 = 0; k0 < D_DIM; k0 += 64){
    // async W tiles -> LDS (linear dest, inverse-swizzled source)
    #pragma unroll
    for (int p = 0; p < 4; ++p){
      gload_lds16(wsrcH[p] + k0, &WH[p * 2048 + wlds_base]);
      gload_lds16(wsrcL[p] + k0, &WL[p * 2048 + wlds_base]);
    }
    // x tile: load f32, split to bf16 hi/lo, swizzled ds_write
    #pragma unroll
    for (int p = 0; p < 4; ++p){
      float4 v = *(const float4*)(xptr[p] + k0);
      u32 h0_ = f2bf_u(v.x), h1_ = f2bf_u(v.y), h2_ = f2bf_u(v.z), h3_ = f2bf_u(v.w);
      u32 l0_ = f2bf_u(v.x - bf2f(h0_)), l1_ = f2bf_u(v.y - bf2f(h1_));
      u32 l2_ = f2bf_u(v.z - bf2f(h2_)), l3_ = f2bf_u(v.w - bf2f(h3_));
      int row = xlrow[p];
      int idx = row * 64 + ((xchunk ^ (row & 7)) << 3) + xoff * 4;
      *(uint2*)&XH[idx] = make_uint2(h0_ | (h1_ << 16), h2_ | (h3_ << 16));
      *(uint2*)&XL[idx] = make_uint2(l0_ | (l1_ << 16), l2_ | (l3_ << 16));
    }
    __syncthreads();   // drains vmcnt (W dma) + lgkm (x writes)

    #pragma unroll
    for (int ks = 0; ks < 2; ++ks){
      bf16x8 ah[2], al[2], bh[4], bl[4];
      const int chunk = ks * 4 + (l >> 4);
      #pragma unroll
      for (int mt = 0; mt < 2; ++mt){
        int row = wm * 32 + mt * 16 + (l & 15);
        int idx = row * 64 + ((chunk ^ (row & 7)) << 3);
        ah[mt] = *(const bf16x8*)&XH[idx];
        al[mt] = *(const bf16x8*)&XL[idx];
      }
      #pragma unroll
      for (int nt = 0; nt < 4; ++nt){
        int row = wn * 64 + nt * 16 + (l & 15);
        int idx = row * 64 + ((chunk ^ (row & 7)) << 3);
        bh[nt] = *(const bf16x8*)&WH[idx];
        bl[nt] = *(const bf16x8*)&WL[idx];
      }
      #pragma unroll
      for (int mt = 0; mt < 2; ++mt)
        #pragma unroll
        for (int nt = 0; nt < 4; ++nt){
          acc[mt][nt] = __builtin_amdgcn_mfma_f32_16x16x32_bf16(ah[mt], bh[nt], acc[mt][nt], 0, 0, 0);
          acc[mt][nt] = __builtin_amdgcn_mfma_f32_16x16x32_bf16(ah[mt], bl[nt], acc[mt][nt], 0, 0, 0);
          acc[mt][nt] = __builtin_amdgcn_mfma_f32_16x16x32_bf16(al[mt], bh[nt], acc[mt][nt], 0, 0, 0);
        }
    }
    __syncthreads();
  }

  // epilogue: z -> tanh(z+b1)*W2, reduce over this block's 128 cols
  // acc[mt][nt] reg j: local row = wm*32+mt*16+(l>>4)*4+j, local col = wn*64+nt*16+(l&15)
  #pragma unroll
  for (int mt = 0; mt < 2; ++mt){
    float rsum[4] = {0.f, 0.f, 0.f, 0.f};
    #pragma unroll
    for (int nt = 0; nt < 4; ++nt){
      int h = h0 + wn * 64 + nt * 16 + (l & 15);
      float w2v = w2[h], b1v = b1[h];
      #pragma unroll
      for (int j = 0; j < 4; ++j)
        rsum[j] += tanhf(acc[mt][nt][j] + b1v) * w2v;
    }
    #pragma unroll
    for (int off = 1; off < 16; off <<= 1)
      #pragma unroll
      for (int j = 0; j < 4; ++j) rsum[j] += __shfl_xor(rsum[j], off, 64);
    if ((l & 15) == 0){
      int g = l >> 4;
      #pragma unroll
      for (int j = 0; j < 4; ++j) EPI[wm * 32 + mt * 16 + g * 4 + j][wn] = rsum[j];
    }
  }
  __syncthreads();
  if (t < 64){
    int n = r0 + t;
    if (n < N_ROWS) partial[(size_t)blockIdx.y * N_ROWS + n] = EPI[t][0] + EPI[t][1];
  }
}

// ---------------- score reduce + 16-bit-bin histogram ----------------
__global__ void reduce_hist(const float* __restrict__ partial, float* __restrict__ scores,
                            u32* __restrict__ hist){
  int n = blockIdx.x * 256 + threadIdx.x;
  if (n >= N_ROWS) return;
  float s = partial[n] + partial[N_ROWS + n] + partial[2 * N_ROWS + n] + partial[3 * N_ROWS + n];
  scores[n] = s;                     // b2 omitted: cancels in softmax + top-k
  atomicAdd(&hist[mono_bits(s) >> 16], 1u);
}

// ---------------- find threshold bin (suffix count >= KSEL) ----------------
__global__ void scan_thresh(const u32* __restrict__ hist, int* __restrict__ meta){
  __shared__ u32 csum[256];
  int t = threadIdx.x;
  u32 s = 0;
  int base = t * 256;
  for (int i = 0; i < 256; ++i) s += hist[base + i];
  csum[t] = s;
  __syncthreads();
  if (t == 0){
    u32 acc = 0; int T = 0;
    for (int c = 255; c >= 0; --c){
      if (acc + csum[c] >= (u32)KSEL){
        u32 cnt = acc;
        for (int b = c * 256 + 255; b >= c * 256; --b){
          cnt += hist[b];
          if (cnt >= (u32)KSEL){ T = b; break; }
        }
        break;
      }
      acc += csum[c];
    }
    meta[0] = T;
  }
}

// ---------------- compact candidates (bins >= threshold bin) ----------------
__global__ void compact_cand(const float* __restrict__ scores, int* __restrict__ meta,
                             u64* __restrict__ keys){
  int n = blockIdx.x * 256 + threadIdx.x;
  if (n >= N_ROWS) return;
  u32 u = mono_bits(scores[n]);
  if ((int)(u >> 16) >= meta[0]){
    int p = atomicAdd(&meta[1], 1);
    if (p < SORT_N) keys[p] = ((u64)u << 32) | (u32)(~n);   // value desc, index asc
  }
}

// ---------------- one-block bitonic sort (desc) + emit exact top-k ----------------
__global__ __launch_bounds__(512) void sort_topk(const u64* __restrict__ keys, const int* __restrict__ meta,
                                                 const float* __restrict__ scores,
                                                 u32* __restrict__ sidx, float* __restrict__ svals){
  __shared__ u64 k_[SORT_N];
  int t = threadIdx.x;
  int C = meta[1]; if (C > SORT_N) C = SORT_N;
  for (int i = t; i < SORT_N; i += 512) k_[i] = (i < C) ? keys[i] : 0ull;
  __syncthreads();
  for (int size = 2; size <= SORT_N; size <<= 1){
    for (int stride = size >> 1; stride > 0; stride >>= 1){
      for (int q = 0; q < SORT_N; q += 512){
        int i = q + t, j = i ^ stride;
        if (j > i){
          u64 a = k_[i], b = k_[j];
          bool desc = ((i & size) == 0);
          if (desc ? (a < b) : (a > b)){ k_[i] = b; k_[j] = a; }
        }
      }
      __syncthreads();
    }
  }
  for (int j = t; j < KSEL; j += 512){
    u32 idx = ~(u32)(k_[j] & 0xFFFFFFFFull);
    sidx[j] = idx;
    svals[j] = scores[idx];
  }
}

// ---------------- softmax over top-k (Z cancels; renormalize over selected) ----------------
__global__ __launch_bounds__(512) void softmax_topk(const float* __restrict__ svals,
                                                    float* __restrict__ akw, float* __restrict__ out){
  __shared__ float red[512];
  int t = threadIdx.x;
  float m = svals[0];                       // sorted desc -> global max
  float local = 0.f;
  for (int j = t; j < KSEL; j += 512){ float e = __expf(0.f) * expf(svals[j] - m); akw[j] = e; local += e; }
  red[t] = local;
  __syncthreads();
  for (int s = 256; s > 0; s >>= 1){ if (t < s) red[t] += red[t + s]; __syncthreads(); }
  float S = red[0];
  for (int j = t; j < KSEL; j += 512){ float a = akw[j] / S; akw[j] = a; out[2048 + j] = a; }
}

// ---------------- gather + weighted sum (deterministic 2-pass) ----------------
__global__ void gather_M(const float* __restrict__ x, const u32* __restrict__ sidx,
                         const float* __restrict__ akw, float* __restrict__ gpart){
  int t = threadIdx.x, b = blockIdx.x;
  float a8[8] = {0.f,0.f,0.f,0.f,0.f,0.f,0.f,0.f};
  for (int j = b; j < KSEL; j += 64){
    float a = akw[j];
    const float* xr = x + (size_t)sidx[j] * D_DIM;
    #pragma unroll
    for (int c = 0; c < 8; ++c) a8[c] += a * xr[t + c * 256];
  }
  #pragma unroll
  for (int c = 0; c < 8; ++c) gpart[(size_t)b * D_DIM + t + c * 256] = a8[c];
}
__global__ void reduce_M(const float* __restrict__ gpart, float* __restrict__ out){
  int d = blockIdx.x * 256 + threadIdx.x;
  float s = 0.f;
  for (int b = 0; b < 64; ++b) s += gpart[(size_t)b * D_DIM + d];
  out[d] = s;
}

extern "C" void kernel_launch(void* const* d_in, const int* in_sizes, int n_in,
                              void* d_out, int out_size, void* d_ws, size_t ws_size,
                              hipStream_t stream) {
  const float* x  = (const float*)d_in[0];
  const float* W1 = (const float*)d_in[1];
  const float* b1 = (const float*)d_in[2];
  const float* W2 = (const float*)d_in[3];
  // b2 (d_in[4]) cancels in softmax/top-k -> unused
  float* out = (float*)d_out;
  char* ws = (char*)d_ws;

  u16* w1h     = (u16*)(ws + W1H_OFF);
  u16* w1l     = (u16*)(ws + W1L_OFF);
  float* part  = (float*)(ws + PART_OFF);
  float* scr   = (float*)(ws + SCORES_OFF);
  u32* hist    = (u32*)(ws + HIST_OFF);
  int* meta    = (int*)(ws + META_OFF);
  u64* keys    = (u64*)(ws + KEYS_OFF);
  u32* sidx    = (u32*)(ws + SIDX_OFF);
  float* svals = (float*)(ws + SVAL_OFF);
  float* akw   = (float*)(ws + AKW_OFF);
  float* gpart = (float*)(ws + GPART_OFF);

  (void)in_sizes; (void)n_in; (void)out_size; (void)ws_size;

  hipMemsetAsync(ws + HIST_OFF, 0, 262144 + 64, stream);   // hist + meta
  prep_w1<<<1024, 256, 0, stream>>>(W1, w1h, w1l);
  gemm_scores<<<dim3(782, 4), 256, 0, stream>>>(x, w1h, w1l, b1, W2, part);
  reduce_hist<<<196, 256, 0, stream>>>(part, scr, hist);
  scan_thresh<<<1, 256, 0, stream>>>(hist, meta);
  compact_cand<<<196, 256, 0, stream>>>(scr, meta, keys);
  sort_topk<<<1, 512, 0, stream>>>(keys, meta, scr, sidx, svals);
  softmax_topk<<<1, 512, 0, stream>>>(svals, akw, out);
  gather_M<<<64, 256, 0, stream>>>(x, sidx, akw, gpart);
  reduce_M<<<8, 256, 0, stream>>>(gpart, out);
}

// Round 2
// 686.088 us; speedup vs baseline: 1.0175x; 1.0175x over previous
//
#include <hip/hip_runtime.h>

typedef unsigned short u16;
typedef unsigned int   u32;
typedef unsigned long long u64;
typedef short bf16x8 __attribute__((ext_vector_type(8)));
typedef float f32x4  __attribute__((ext_vector_type(4)));

#define N_ROWS 50000
#define D_DIM  2048
#define H_DIM  512
#define KSEL   5000
#define SORT_N 8192

// ---------- workspace layout (bytes) ----------
#define W1H_OFF    0u           // 512*2048 bf16 hi (2 MB)
#define W1L_OFF    2097152u     // 512*2048 bf16 lo (2 MB)
#define PART_OFF   4194304u     // 2 x 50000 f32 (400 KB)
#define SCORES_OFF 4596736u     // 50000 f32
#define HIST_OFF   4798464u     // 65536 u32
#define AKW_OFF    5060608u     // 5000 f32
#define SIDX_OFF   5080832u     // 5000 u32
#define GPART_OFF  5101056u     // 128*2048 f32 (1 MB)
#define SMALL_END  6149632u
#define XH_OFF     8388608u     // 50000*2048 bf16 (204.8 MB)
#define XL_OFF     213188608u   // 50000*2048 bf16
#define WS_PS_NEED 417988608ull // XL end

__device__ __forceinline__ u32 f2bf_u(float f){
  u32 u = __float_as_uint(f);
  return (u + 0x7FFFu + ((u >> 16) & 1u)) >> 16;   // RNE
}
__device__ __forceinline__ float bf2f(u32 h){ return __uint_as_float(h << 16); }
__device__ __forceinline__ u32 mono_bits(float s){
  u32 u = __float_as_uint(s);
  return (u & 0x80000000u) ? ~u : (u | 0x80000000u);
}
__device__ __forceinline__ void gload_lds16(const void* g, void* l){
  __builtin_amdgcn_global_load_lds((__attribute__((address_space(1))) void*)(void*)g,
                                   (__attribute__((address_space(3))) void*)l, 16, 0, 0);
}
__device__ __forceinline__ void split8(const float* f, uint4& H, uint4& L){
  u32 hh[8], ll[8];
  #pragma unroll
  for (int i = 0; i < 8; ++i){
    hh[i] = f2bf_u(f[i]);
    ll[i] = f2bf_u(f[i] - bf2f(hh[i]));
  }
  H = make_uint4(hh[0]|(hh[1]<<16), hh[2]|(hh[3]<<16), hh[4]|(hh[5]<<16), hh[6]|(hh[7]<<16));
  L = make_uint4(ll[0]|(ll[1]<<16), ll[2]|(ll[3]<<16), ll[4]|(ll[5]<<16), ll[6]|(ll[7]<<16));
}

// ---------- W1 -> bf16 hi/lo ----------
__global__ void prep_w1(const float* __restrict__ w1, u16* __restrict__ w1h, u16* __restrict__ w1l){
  int i = (blockIdx.x * 256 + threadIdx.x) * 4;
  float4 v = *(const float4*)(w1 + i);
  u32 h0 = f2bf_u(v.x), h1 = f2bf_u(v.y), h2 = f2bf_u(v.z), h3 = f2bf_u(v.w);
  u32 l0 = f2bf_u(v.x - bf2f(h0)), l1 = f2bf_u(v.y - bf2f(h1));
  u32 l2 = f2bf_u(v.z - bf2f(h2)), l3 = f2bf_u(v.w - bf2f(h3));
  *(uint2*)(w1h + i) = make_uint2(h0 | (h1 << 16), h2 | (h3 << 16));
  *(uint2*)(w1l + i) = make_uint2(l0 | (l1 << 16), l2 | (l3 << 16));
}

// ---------- x -> bf16 hi/lo (one block per row) ----------
__global__ void prep_x(const float* __restrict__ x, u16* __restrict__ xh, u16* __restrict__ xl){
  size_t base = (size_t)blockIdx.x * D_DIM + threadIdx.x * 8;
  float4 v0 = *(const float4*)(x + base);
  float4 v1 = *(const float4*)(x + base + 4);
  float f[8] = {v0.x, v0.y, v0.z, v0.w, v1.x, v1.y, v1.z, v1.w};
  uint4 H, L;
  split8(f, H, L);
  *(uint4*)(xh + base) = H;
  *(uint4*)(xl + base) = L;
}

// ---------- fused scores GEMM ----------
// grid (2, 782): block = 64 rows x 256 h-cols. 4 waves, wave-tile 64x64 (wave w owns
// cols w*64..w*64+63). Split-bf16: z = xh*wh + xh*wl + xl*wh (3 MFMA / frag pair).
// Epilogue: tanh(z+b1)*W2 reduced over block's 256 cols -> partial[by][row].
template<bool PS>
__global__ __launch_bounds__(256, 2) void gemm_scores2(
    const float* __restrict__ x, const u16* __restrict__ xh, const u16* __restrict__ xl,
    const u16* __restrict__ w1h, const u16* __restrict__ w1l,
    const float* __restrict__ b1, const float* __restrict__ w2, float* __restrict__ partial)
{
  __shared__ __align__(16) u16 XH[4096], XL[4096];     //  64 x 64k, 8 KB each
  __shared__ __align__(16) u16 WH[16384], WL[16384];   // 256 x 64k, 32 KB each

  const int t  = threadIdx.x;
  const int l  = t & 63, w = t >> 6;
  const int h0 = blockIdx.x * 256;
  const int r0 = blockIdx.y * 64;

  f32x4 acc[4][4] = {};

  // staging geometry: one gload pass = 8 rows (lane: row += l>>3, slot = l&7),
  // source chunk pre-swizzled: chunk = slot ^ (row&7)
  const int lrow   = l >> 3;
  const int lchunk = (l & 7) ^ lrow;          // global 16B-chunk index to fetch
  const int wrow   = w * 8 + lrow;            // + p*32

  const u16* wsH = w1h + (size_t)(h0 + wrow) * D_DIM + lchunk * 8;
  const u16* wsL = w1l + (size_t)(h0 + wrow) * D_DIM + lchunk * 8;

  const u16* xsH[2]; const u16* xsL[2];
  const float* xf;            // fallback path
  int xrow_f = 0;
  if constexpr (PS){
    #pragma unroll
    for (int p = 0; p < 2; ++p){
      int gr = r0 + p * 32 + wrow; if (gr > N_ROWS - 1) gr = N_ROWS - 1;
      xsH[p] = xh + (size_t)gr * D_DIM + lchunk * 8;
      xsL[p] = xl + (size_t)gr * D_DIM + lchunk * 8;
    }
  } else {
    xrow_f = t >> 2;
    int gr = r0 + xrow_f; if (gr > N_ROWS - 1) gr = N_ROWS - 1;
    xf = x + (size_t)gr * D_DIM;
  }

  for (int k0 = 0; k0 < D_DIM; k0 += 64){
    // W tiles: 8 passes x 2 arrays, async direct-to-LDS
    #pragma unroll
    for (int p = 0; p < 8; ++p){
      gload_lds16(wsH + (size_t)p * 32 * D_DIM + k0, &WH[(p * 32 + w * 8) * 64]);
      gload_lds16(wsL + (size_t)p * 32 * D_DIM + k0, &WL[(p * 32 + w * 8) * 64]);
    }
    if constexpr (PS){
      #pragma unroll
      for (int p = 0; p < 2; ++p){
        gload_lds16(xsH[p] + k0, &XH[(p * 32 + w * 8) * 64]);
        gload_lds16(xsL[p] + k0, &XL[(p * 32 + w * 8) * 64]);
      }
    } else {
      // in-loop split: thread t -> row t>>2, slots (t&3)*2 + {0,1}
      #pragma unroll
      for (int ss = 0; ss < 2; ++ss){
        int s = (t & 3) * 2 + ss;
        int c = s ^ (xrow_f & 7);
        float f[8];
        float4 v0 = *(const float4*)(xf + k0 + c * 8);
        float4 v1 = *(const float4*)(xf + k0 + c * 8 + 4);
        f[0]=v0.x; f[1]=v0.y; f[2]=v0.z; f[3]=v0.w; f[4]=v1.x; f[5]=v1.y; f[6]=v1.z; f[7]=v1.w;
        uint4 H, L; split8(f, H, L);
        *(uint4*)&XH[xrow_f * 64 + s * 8] = H;
        *(uint4*)&XL[xrow_f * 64 + s * 8] = L;
      }
    }
    __syncthreads();   // drains vmcnt (gload_lds) + lgkm (ds_writes)

    #pragma unroll
    for (int ks = 0; ks < 2; ++ks){
      const int chunk = ks * 4 + (l >> 4);
      bf16x8 ah[4], al[4], bh[4], bl[4];
      #pragma unroll
      for (int mt = 0; mt < 4; ++mt){
        int row = mt * 16 + (l & 15);
        int idx = row * 64 + ((chunk ^ (row & 7)) << 3);
        ah[mt] = *(const bf16x8*)&XH[idx];
        al[mt] = *(const bf16x8*)&XL[idx];
      }
      #pragma unroll
      for (int nt = 0; nt < 4; ++nt){
        int row = w * 64 + nt * 16 + (l & 15);
        int idx = row * 64 + ((chunk ^ (row & 7)) << 3);
        bh[nt] = *(const bf16x8*)&WH[idx];
        bl[nt] = *(const bf16x8*)&WL[idx];
      }
      #pragma unroll
      for (int mt = 0; mt < 4; ++mt)
        #pragma unroll
        for (int nt = 0; nt < 4; ++nt){
          acc[mt][nt] = __builtin_amdgcn_mfma_f32_16x16x32_bf16(ah[mt], bh[nt], acc[mt][nt], 0, 0, 0);
          acc[mt][nt] = __builtin_amdgcn_mfma_f32_16x16x32_bf16(ah[mt], bl[nt], acc[mt][nt], 0, 0, 0);
          acc[mt][nt] = __builtin_amdgcn_mfma_f32_16x16x32_bf16(al[mt], bh[nt], acc[mt][nt], 0, 0, 0);
        }
    }
    __syncthreads();
  }

  // epilogue: tanh(z+b1)*w2, reduce over cols. acc reg j: row = mt*16+(l>>4)*4+j, col = l&15
  float (*EPI)[4] = (float(*)[4])XH;   // alias (K-loop done, all waves past final barrier)
  #pragma unroll
  for (int mt = 0; mt < 4; ++mt){
    float rsum[4] = {0.f, 0.f, 0.f, 0.f};
    #pragma unroll
    for (int nt = 0; nt < 4; ++nt){
      int h = h0 + w * 64 + nt * 16 + (l & 15);
      float w2v = w2[h], b1v = b1[h];
      #pragma unroll
      for (int j = 0; j < 4; ++j)
        rsum[j] += tanhf(acc[mt][nt][j] + b1v) * w2v;
    }
    #pragma unroll
    for (int off = 1; off < 16; off <<= 1)
      #pragma unroll
      for (int j = 0; j < 4; ++j) rsum[j] += __shfl_xor(rsum[j], off, 64);
    if ((l & 15) == 0){
      int g = l >> 4;
      #pragma unroll
      for (int j = 0; j < 4; ++j) EPI[mt * 16 + g * 4 + j][w] = rsum[j];
    }
  }
  __syncthreads();
  if (t < 64){
    int n = r0 + t;
    if (n < N_ROWS)
      partial[(size_t)blockIdx.x * N_ROWS + n] = EPI[t][0] + EPI[t][1] + EPI[t][2] + EPI[t][3];
  }
}

// ---------- score reduce + 16-bit-bin histogram ----------
__global__ void reduce_hist(const float* __restrict__ partial, float* __restrict__ scores,
                            u32* __restrict__ hist){
  int n = blockIdx.x * 256 + threadIdx.x;
  if (n >= N_ROWS) return;
  float s = partial[n] + partial[N_ROWS + n];     // b2 omitted: cancels
  scores[n] = s;
  atomicAdd(&hist[mono_bits(s) >> 16], 1u);
}

// ---------- fused: threshold scan + compact + bitonic sort + softmax ----------
__global__ __launch_bounds__(1024) void topk_fused(
    const u32* __restrict__ hist, const float* __restrict__ scores,
    float* __restrict__ akw, u32* __restrict__ sidx, float* __restrict__ out)
{
  __shared__ u64 KEY[SORT_N];        // 64 KB
  __shared__ u32 csum[1024];
  __shared__ float red[1024];
  __shared__ int sh_c, sh_T, sh_cnt;
  const int t = threadIdx.x;

  // 1. per-chunk sums (64 bins each) + suffix scan
  u32 s = 0;
  for (int i = 0; i < 64; ++i) s += hist[t * 64 + i];
  csum[t] = s;
  __syncthreads();
  for (int off = 1; off < 1024; off <<= 1){
    u32 v = (t + off < 1024) ? csum[t + off] : 0u;
    __syncthreads();
    csum[t] += v;
    __syncthreads();
  }
  if (csum[t] >= (u32)KSEL && (t == 1023 || csum[t + 1] < (u32)KSEL)) sh_c = t;
  __syncthreads();
  if (t == 0){
    int c = sh_c;
    u32 cnt = (c < 1023) ? csum[c + 1] : 0u;
    int T = c * 64;
    for (int b = c * 64 + 63; b >= c * 64; --b){
      cnt += hist[b];
      if (cnt >= (u32)KSEL){ T = b; break; }
    }
    sh_T = T; sh_cnt = 0;
  }
  __syncthreads();

  // 2. compact candidates into LDS
  const int T = sh_T;
  for (int n = t; n < N_ROWS; n += 1024){
    u32 u = mono_bits(scores[n]);
    if ((int)(u >> 16) >= T){
      int p = atomicAdd(&sh_cnt, 1);
      if (p < SORT_N) KEY[p] = ((u64)u << 32) | (u32)(~n);   // value desc, idx asc
    }
  }
  __syncthreads();
  int C = sh_cnt; if (C > SORT_N) C = SORT_N;
  for (int i = t; i < SORT_N; i += 1024) if (i >= C) KEY[i] = 0ull;
  __syncthreads();

  // 3. bitonic sort desc
  for (int size = 2; size <= SORT_N; size <<= 1){
    for (int stride = size >> 1; stride > 0; stride >>= 1){
      for (int q = 0; q < SORT_N; q += 1024){
        int i = q + t, j = i ^ stride;
        if (j > i){
          u64 a = KEY[i], b = KEY[j];
          bool desc = ((i & size) == 0);
          if (desc ? (a < b) : (a > b)){ KEY[i] = b; KEY[j] = a; }
        }
      }
      __syncthreads();
    }
  }

  // 4. softmax over top-k (global Z and b2 cancel; renormalize over selected)
  u32 id0 = ~(u32)(KEY[0] & 0xFFFFFFFFull);
  float m = scores[id0];
  float ev[5]; u32 id[5];
  float local = 0.f;
  #pragma unroll
  for (int r = 0; r < 5; ++r){
    int j = t + r * 1024;
    if (j < KSEL){
      id[r] = ~(u32)(KEY[j] & 0xFFFFFFFFull);
      ev[r] = expf(scores[id[r]] - m);
      local += ev[r];
    }
  }
  red[t] = local;
  __syncthreads();
  for (int o = 512; o > 0; o >>= 1){ if (t < o) red[t] += red[t + o]; __syncthreads(); }
  float S = red[0];
  #pragma unroll
  for (int r = 0; r < 5; ++r){
    int j = t + r * 1024;
    if (j < KSEL){
      float a = ev[r] / S;
      akw[j] = a; sidx[j] = id[r]; out[D_DIM + j] = a;
    }
  }
}

// ---------- gather + weighted sum (deterministic 2-pass) ----------
__global__ void gather_M(const float* __restrict__ x, const u32* __restrict__ sidx,
                         const float* __restrict__ akw, float* __restrict__ gpart){
  int t = threadIdx.x, b = blockIdx.x;   // 128 blocks
  float a8[8] = {0.f,0.f,0.f,0.f,0.f,0.f,0.f,0.f};
  for (int j = b; j < KSEL; j += 128){
    float a = akw[j];
    const float* xr = x + (size_t)sidx[j] * D_DIM;
    #pragma unroll
    for (int c = 0; c < 8; ++c) a8[c] += a * xr[t + c * 256];
  }
  #pragma unroll
  for (int c = 0; c < 8; ++c) gpart[(size_t)b * D_DIM + t + c * 256] = a8[c];
}
__global__ void reduce_M(const float* __restrict__ gpart, float* __restrict__ out){
  int d = blockIdx.x * 256 + threadIdx.x;
  float s = 0.f;
  for (int b = 0; b < 128; ++b) s += gpart[(size_t)b * D_DIM + d];
  out[d] = s;
}

extern "C" void kernel_launch(void* const* d_in, const int* in_sizes, int n_in,
                              void* d_out, int out_size, void* d_ws, size_t ws_size,
                              hipStream_t stream) {
  const float* x  = (const float*)d_in[0];
  const float* W1 = (const float*)d_in[1];
  const float* b1 = (const float*)d_in[2];
  const float* W2 = (const float*)d_in[3];
  float* out = (float*)d_out;
  char* ws = (char*)d_ws;

  u16* w1h     = (u16*)(ws + W1H_OFF);
  u16* w1l     = (u16*)(ws + W1L_OFF);
  float* part  = (float*)(ws + PART_OFF);
  float* scr   = (float*)(ws + SCORES_OFF);
  u32* hist    = (u32*)(ws + HIST_OFF);
  float* akw   = (float*)(ws + AKW_OFF);
  u32* sidx    = (u32*)(ws + SIDX_OFF);
  float* gpart = (float*)(ws + GPART_OFF);
  u16* xh      = (u16*)(ws + XH_OFF);
  u16* xl      = (u16*)(ws + XL_OFF);

  (void)in_sizes; (void)n_in; (void)out_size;

  hipMemsetAsync(ws + HIST_OFF, 0, 262144, stream);
  prep_w1<<<1024, 256, 0, stream>>>(W1, w1h, w1l);
  if (ws_size >= WS_PS_NEED){
    prep_x<<<N_ROWS, 256, 0, stream>>>(x, xh, xl);
    gemm_scores2<true><<<dim3(2, 782), 256, 0, stream>>>(x, xh, xl, w1h, w1l, b1, W2, part);
  } else {
    gemm_scores2<false><<<dim3(2, 782), 256, 0, stream>>>(x, xh, xl, w1h, w1l, b1, W2, part);
  }
  reduce_hist<<<196, 256, 0, stream>>>(part, scr, hist);
  topk_fused<<<1, 1024, 0, stream>>>(hist, scr, akw, sidx, out);
  gather_M<<<128, 256, 0, stream>>>(x, sidx, akw, gpart);
  reduce_M<<<8, 256, 0, stream>>>(gpart, out);
}

// Round 3
// 410.243 us; speedup vs baseline: 1.7017x; 1.6724x over previous
//
#include <hip/hip_runtime.h>

typedef unsigned short u16;
typedef unsigned int   u32;
typedef unsigned long long u64;
typedef _Float16 f16;
typedef f16 f16x8 __attribute__((ext_vector_type(8)));
typedef f16 f16x4 __attribute__((ext_vector_type(4)));
typedef float f32x4 __attribute__((ext_vector_type(4)));

#define N_ROWS 50000
#define D_DIM  2048
#define H_DIM  512
#define KSEL   5000
#define SORT_N 8192

// ---------- workspace layout (bytes) ----------
#define W1F_OFF    0u          // 512*2048 f16 (2 MB)
#define PART_OFF   2097152u    // 2 x 50000 f32 (400 KB)
#define SCORES_OFF 2555904u    // 50000 f32
#define HIST_OFF   2752512u    // 65536 u32 (256 KB)
#define AKW_OFF    3014656u    // 5000 f32
#define SIDX_OFF   3047424u    // 5000 u32
#define GPART_OFF  3080192u    // 256*2048 f32 (2 MB)

__device__ __forceinline__ u32 mono_bits(float s){
  u32 u = __float_as_uint(s);
  return (u & 0x80000000u) ? ~u : (u | 0x80000000u);
}
__device__ __forceinline__ void gload_lds16(const void* g, void* l){
  __builtin_amdgcn_global_load_lds((__attribute__((address_space(1))) void*)(void*)g,
                                   (__attribute__((address_space(3))) void*)l, 16, 0, 0);
}

// ---------- W1 -> fp16 ----------
__global__ void prep_w1_f16(const float* __restrict__ w1, f16* __restrict__ w1f){
  int i = (blockIdx.x * 256 + threadIdx.x) * 4;   // 1024*256*4 = 1048576 exact
  float4 v = *(const float4*)(w1 + i);
  f16x4 h;
  h[0] = (f16)v.x; h[1] = (f16)v.y; h[2] = (f16)v.z; h[3] = (f16)v.w;
  *(f16x4*)(w1f + i) = h;
}

// ---------- fused scores GEMM (fp16 single MFMA) ----------
// grid 392 linear -> (bx in 0..1, by in 0..195) via XCD-chunk swizzle.
// Block tile 256 rows x 256 h-cols, BK=64, 8 waves (2M x 4N), wave-tile 128x64.
// Double-buffered LDS (128 KB), stage(next) issued before compute(cur), one
// barrier per K-tile. x read f32 + converted in-kernel (no prep pass).
// Epilogue: tanh(z+b1)*W2 reduced over the block's 256 cols -> partial[bx][row].
__global__ __launch_bounds__(512, 2) void gemm_f16(
    const float* __restrict__ x, const f16* __restrict__ w1f,
    const float* __restrict__ b1, const float* __restrict__ w2, float* __restrict__ partial)
{
  __shared__ __align__(16) f16 At[2][16384];   // 256 rows x 64 k, 32 KB each buf
  __shared__ __align__(16) f16 Bt[2][16384];

  const int t  = threadIdx.x;
  const int l  = t & 63, w = t >> 6;
  const int wm = w >> 2, wn = w & 3;           // 2M x 4N wave grid

  // bijective XCD-chunk swizzle (392 = 49*8)
  int nn = (blockIdx.x % 8) * 49 + blockIdx.x / 8;
  const int bx = nn / 196, by = nn % 196;
  const int h0 = bx * 256, r0 = by * 256;

  f32x4 acc[8][4] = {};

  // W staging: pass p -> row p*64 + w*8 + (l>>3), 16B chunk slot l&7,
  // source chunk pre-swizzled (slot ^ (row&7)); LDS dest lane-linear (= base + l*16B).
  const int srow = w * 8 + (l >> 3);
  const f16* wsrc = w1f + (size_t)(h0 + srow) * D_DIM + ((l & 7) ^ (srow & 7)) * 8;
  const int wdst = (w * 8 + (l >> 3)) * 64 + (l & 7) * 8;   // + p*64*64

  // x staging: pass p -> row p*64 + (t>>3), 8 f32 at k = (t&7)*8
  const int xrow_l = t >> 3;
  const int xc = t & 7;
  const float* xptr[4];
  #pragma unroll
  for (int p = 0; p < 4; ++p){
    int gr = r0 + p * 64 + xrow_l; if (gr > N_ROWS - 1) gr = N_ROWS - 1;
    xptr[p] = x + (size_t)gr * D_DIM + xc * 8;
  }
  const int xdst = xrow_l * 64 + ((xc ^ (xrow_l & 7)) << 3);  // + p*64*64

  // ---- prologue: stage K-tile 0 into buf 0 ----
  {
    #pragma unroll
    for (int p = 0; p < 4; ++p)
      gload_lds16(wsrc + (size_t)p * 64 * D_DIM, &Bt[0][p * 4096 + wdst]);
    float4 xr[4][2];
    #pragma unroll
    for (int p = 0; p < 4; ++p){
      xr[p][0] = *(const float4*)(xptr[p]);
      xr[p][1] = *(const float4*)(xptr[p] + 4);
    }
    #pragma unroll
    for (int p = 0; p < 4; ++p){
      f16x8 v;
      v[0]=(f16)xr[p][0].x; v[1]=(f16)xr[p][0].y; v[2]=(f16)xr[p][0].z; v[3]=(f16)xr[p][0].w;
      v[4]=(f16)xr[p][1].x; v[5]=(f16)xr[p][1].y; v[6]=(f16)xr[p][1].z; v[7]=(f16)xr[p][1].w;
      *(f16x8*)&At[0][p * 4096 + xdst] = v;
    }
  }
  __syncthreads();

  int buf = 0;
  for (int kt = 0; kt < 32; ++kt){
    const int k0n = (kt + 1) * 64;
    float4 xr[4][2];
    if (kt < 31){
      // issue next-tile staging first: x f32 -> regs, W -> LDS direct
      #pragma unroll
      for (int p = 0; p < 4; ++p){
        xr[p][0] = *(const float4*)(xptr[p] + k0n);
        xr[p][1] = *(const float4*)(xptr[p] + k0n + 4);
      }
      #pragma unroll
      for (int p = 0; p < 4; ++p)
        gload_lds16(wsrc + (size_t)p * 64 * D_DIM + k0n, &Bt[buf ^ 1][p * 4096 + wdst]);
    }

    // compute current buffer
    __builtin_amdgcn_s_setprio(1);
    #pragma unroll
    for (int ks = 0; ks < 2; ++ks){
      const int chunk = ks * 4 + (l >> 4);
      f16x8 bfr[4];
      #pragma unroll
      for (int nt = 0; nt < 4; ++nt){
        int row = wn * 64 + nt * 16 + (l & 15);
        bfr[nt] = *(const f16x8*)&Bt[buf][row * 64 + ((chunk ^ (row & 7)) << 3)];
      }
      #pragma unroll
      for (int mt = 0; mt < 8; ++mt){
        int row = wm * 128 + mt * 16 + (l & 15);
        f16x8 af = *(const f16x8*)&At[buf][row * 64 + ((chunk ^ (row & 7)) << 3)];
        #pragma unroll
        for (int nt = 0; nt < 4; ++nt)
          acc[mt][nt] = __builtin_amdgcn_mfma_f32_16x16x32_f16(af, bfr[nt], acc[mt][nt], 0, 0, 0);
      }
    }
    __builtin_amdgcn_s_setprio(0);

    if (kt < 31){
      // cvt + LDS write of next x tile (loads have landed under the MFMA cluster)
      #pragma unroll
      for (int p = 0; p < 4; ++p){
        f16x8 v;
        v[0]=(f16)xr[p][0].x; v[1]=(f16)xr[p][0].y; v[2]=(f16)xr[p][0].z; v[3]=(f16)xr[p][0].w;
        v[4]=(f16)xr[p][1].x; v[5]=(f16)xr[p][1].y; v[6]=(f16)xr[p][1].z; v[7]=(f16)xr[p][1].w;
        *(f16x8*)&At[buf ^ 1][p * 4096 + xdst] = v;
      }
    }
    __syncthreads();   // drains vmcnt (W dma) + lgkm (x writes)
    buf ^= 1;
  }

  // ---- epilogue: tanh(z+b1)*w2, reduce over block's 256 cols ----
  // acc[mt][nt] reg j: row = wm*128 + mt*16 + (l>>4)*4 + j, col = wn*64 + nt*16 + (l&15)
  float (*EPI)[4] = (float(*)[4])At;   // alias: K-loop done, all waves past final barrier
  #pragma unroll
  for (int mt = 0; mt < 8; ++mt){
    float rsum[4] = {0.f, 0.f, 0.f, 0.f};
    #pragma unroll
    for (int nt = 0; nt < 4; ++nt){
      int h = h0 + wn * 64 + nt * 16 + (l & 15);
      float w2v = w2[h], b1v = b1[h];
      #pragma unroll
      for (int j = 0; j < 4; ++j)
        rsum[j] += tanhf(acc[mt][nt][j] + b1v) * w2v;
    }
    #pragma unroll
    for (int off = 1; off < 16; off <<= 1)
      #pragma unroll
      for (int j = 0; j < 4; ++j) rsum[j] += __shfl_xor(rsum[j], off, 64);
    if ((l & 15) == 0){
      int g = l >> 4;
      #pragma unroll
      for (int j = 0; j < 4; ++j) EPI[wm * 128 + mt * 16 + g * 4 + j][wn] = rsum[j];
    }
  }
  __syncthreads();
  if (t < 256){
    int n = r0 + t;
    if (n < N_ROWS)
      partial[(size_t)bx * N_ROWS + n] = EPI[t][0] + EPI[t][1] + EPI[t][2] + EPI[t][3];
  }
}

// ---------- score reduce + 16-bit-bin histogram ----------
__global__ void reduce_hist(const float* __restrict__ partial, float* __restrict__ scores,
                            u32* __restrict__ hist){
  int n = blockIdx.x * 256 + threadIdx.x;
  if (n >= N_ROWS) return;
  float s = partial[n] + partial[N_ROWS + n];     // b2 omitted: cancels in softmax/top-k
  scores[n] = s;
  atomicAdd(&hist[mono_bits(s) >> 16], 1u);
}

// ---------- fused: threshold scan + compact + bitonic sort + softmax ----------
__global__ __launch_bounds__(1024) void topk_fused(
    const u32* __restrict__ hist, const float* __restrict__ scores,
    float* __restrict__ akw, u32* __restrict__ sidx, float* __restrict__ out)
{
  __shared__ u64 KEY[SORT_N];        // 64 KB
  __shared__ u32 csum[1024];
  __shared__ float red[1024];
  __shared__ int sh_c, sh_T, sh_cnt;
  const int t = threadIdx.x;

  u32 s = 0;
  for (int i = 0; i < 64; ++i) s += hist[t * 64 + i];
  csum[t] = s;
  __syncthreads();
  for (int off = 1; off < 1024; off <<= 1){
    u32 v = (t + off < 1024) ? csum[t + off] : 0u;
    __syncthreads();
    csum[t] += v;
    __syncthreads();
  }
  if (csum[t] >= (u32)KSEL && (t == 1023 || csum[t + 1] < (u32)KSEL)) sh_c = t;
  __syncthreads();
  if (t == 0){
    int c = sh_c;
    u32 cnt = (c < 1023) ? csum[c + 1] : 0u;
    int T = c * 64;
    for (int b = c * 64 + 63; b >= c * 64; --b){
      cnt += hist[b];
      if (cnt >= (u32)KSEL){ T = b; break; }
    }
    sh_T = T; sh_cnt = 0;
  }
  __syncthreads();

  const int T = sh_T;
  for (int n = t; n < N_ROWS; n += 1024){
    u32 u = mono_bits(scores[n]);
    if ((int)(u >> 16) >= T){
      int p = atomicAdd(&sh_cnt, 1);
      if (p < SORT_N) KEY[p] = ((u64)u << 32) | (u32)(~n);   // value desc, idx asc
    }
  }
  __syncthreads();
  int C = sh_cnt; if (C > SORT_N) C = SORT_N;
  for (int i = t; i < SORT_N; i += 1024) if (i >= C) KEY[i] = 0ull;
  __syncthreads();

  for (int size = 2; size <= SORT_N; size <<= 1){
    for (int stride = size >> 1; stride > 0; stride >>= 1){
      for (int q = 0; q < SORT_N; q += 1024){
        int i = q + t, j = i ^ stride;
        if (j > i){
          u64 a = KEY[i], b = KEY[j];
          bool desc = ((i & size) == 0);
          if (desc ? (a < b) : (a > b)){ KEY[i] = b; KEY[j] = a; }
        }
      }
      __syncthreads();
    }
  }

  u32 id0 = ~(u32)(KEY[0] & 0xFFFFFFFFull);
  float m = scores[id0];
  float ev[5]; u32 id[5];
  float local = 0.f;
  #pragma unroll
  for (int r = 0; r < 5; ++r){
    int j = t + r * 1024;
    if (j < KSEL){
      id[r] = ~(u32)(KEY[j] & 0xFFFFFFFFull);
      ev[r] = expf(scores[id[r]] - m);
      local += ev[r];
    }
  }
  red[t] = local;
  __syncthreads();
  for (int o = 512; o > 0; o >>= 1){ if (t < o) red[t] += red[t + o]; __syncthreads(); }
  float S = red[0];
  #pragma unroll
  for (int r = 0; r < 5; ++r){
    int j = t + r * 1024;
    if (j < KSEL){
      float a = ev[r] / S;
      akw[j] = a; sidx[j] = id[r]; out[D_DIM + j] = a;
    }
  }
}

// ---------- gather + weighted sum (deterministic 2-pass) ----------
__global__ void gather_M(const float* __restrict__ x, const u32* __restrict__ sidx,
                         const float* __restrict__ akw, float* __restrict__ gpart){
  int t = threadIdx.x, b = blockIdx.x;   // 256 blocks
  float a8[8] = {0.f,0.f,0.f,0.f,0.f,0.f,0.f,0.f};
  for (int j = b; j < KSEL; j += 256){
    float a = akw[j];
    const float* xr = x + (size_t)sidx[j] * D_DIM;
    #pragma unroll
    for (int c = 0; c < 8; ++c) a8[c] += a * xr[t + c * 256];
  }
  #pragma unroll
  for (int c = 0; c < 8; ++c) gpart[(size_t)b * D_DIM + t + c * 256] = a8[c];
}
__global__ void reduce_M(const float* __restrict__ gpart, float* __restrict__ out){
  int d = blockIdx.x * 256 + threadIdx.x;
  float s = 0.f;
  for (int b = 0; b < 256; ++b) s += gpart[(size_t)b * D_DIM + d];
  out[d] = s;
}

extern "C" void kernel_launch(void* const* d_in, const int* in_sizes, int n_in,
                              void* d_out, int out_size, void* d_ws, size_t ws_size,
                              hipStream_t stream) {
  const float* x  = (const float*)d_in[0];
  const float* W1 = (const float*)d_in[1];
  const float* b1 = (const float*)d_in[2];
  const float* W2 = (const float*)d_in[3];
  // b2 (d_in[4]) cancels in softmax/top-k -> unused
  float* out = (float*)d_out;
  char* ws = (char*)d_ws;

  f16* w1f     = (f16*)(ws + W1F_OFF);
  float* part  = (float*)(ws + PART_OFF);
  float* scr   = (float*)(ws + SCORES_OFF);
  u32* hist    = (u32*)(ws + HIST_OFF);
  float* akw   = (float*)(ws + AKW_OFF);
  u32* sidx    = (u32*)(ws + SIDX_OFF);
  float* gpart = (float*)(ws + GPART_OFF);

  (void)in_sizes; (void)n_in; (void)out_size; (void)ws_size;

  hipMemsetAsync(ws + HIST_OFF, 0, 262144, stream);
  prep_w1_f16<<<1024, 256, 0, stream>>>(W1, w1f);
  gemm_f16<<<392, 512, 0, stream>>>(x, w1f, b1, W2, part);
  reduce_hist<<<196, 256, 0, stream>>>(part, scr, hist);
  topk_fused<<<1, 1024, 0, stream>>>(hist, scr, akw, sidx, out);
  gather_M<<<256, 256, 0, stream>>>(x, sidx, akw, gpart);
  reduce_M<<<8, 256, 0, stream>>>(gpart, out);
}